// Round 6
// baseline (326.020 us; speedup 1.0000x reference)
//
#include <hip/hip_runtime.h>

// Problem constants (from reference)
#define DIM_IN   2048
#define FEAT     128
#define KP1      16385      // NCE_N + 1
#define NDATA    100000
#define BATCH    64
#define RT       256        // rows per gemm tile
#define KW       32         // K-pass width (4 passes of 32)
#define NTILES   ((NDATA + RT - 1) / RT)   // 391
#define GCH      8          // k-chunks per (side,b) in gather kernel

constexpr float NCE_T_INV = 1.0f / 0.07f;
constexpr float M_CONST   = 16384.0f / 100000.0f;   // NCE_N / N_DATA
constexpr float EPS_C     = 1e-7f;

// ---------------------------------------------------------------------------
// Kernel 1: h = l2norm(feat @ w.T + b). Per-wave coalesced row dots.
// ---------------------------------------------------------------------------
__global__ void __launch_bounds__(256) embed_kernel(
    const float* __restrict__ feat_s, const float* __restrict__ feat_t,
    const float* __restrict__ w_s, const float* __restrict__ b_s,
    const float* __restrict__ w_t, const float* __restrict__ b_t,
    float* __restrict__ v_out)
{
    const int blk  = blockIdx.x;      // side*64 + b
    const int side = blk >> 6;
    const int b    = blk & 63;
    const float* feat = (side == 0 ? feat_s : feat_t) + (size_t)b * DIM_IN;
    const float* w    = (side == 0 ? w_s : w_t);
    const float* bias = (side == 0 ? b_s : b_t);

    __shared__ float sfeat[DIM_IN];
    __shared__ float pre[FEAT];
    __shared__ float wsum[2];

    const int t = threadIdx.x;
    {   // coalesced float4 stage of the feat row (8 KB)
        const float4* f4 = (const float4*)feat;
        float4* s4 = (float4*)sfeat;
        for (int j = t; j < DIM_IN / 4; j += 256) s4[j] = f4[j];
    }
    __syncthreads();

    const int wv = t >> 6, ln = t & 63;
    const float4* w4  = (const float4*)w;
    const float4* sf4 = (const float4*)sfeat;
    for (int d = wv; d < FEAT; d += 4) {
        float s = 0.f;
#pragma unroll
        for (int seg = 0; seg < 8; ++seg) {      // 512 float4 per row / 64 lanes
            float4 a = w4[d * (DIM_IN / 4) + seg * 64 + ln];
            float4 f = sf4[seg * 64 + ln];
            s += a.x * f.x + a.y * f.y + a.z * f.z + a.w * f.w;
        }
#pragma unroll
        for (int o = 32; o > 0; o >>= 1) s += __shfl_xor(s, o, 64);
        if (ln == 0) pre[d] = s;
    }
    __syncthreads();

    if (t < 128) {
        float p = pre[t] + bias[t];
        pre[t] = p;
        float sq = p * p;
#pragma unroll
        for (int o = 32; o > 0; o >>= 1) sq += __shfl_xor(sq, o, 64);
        if ((t & 63) == 0) wsum[t >> 6] = sq;
    }
    __syncthreads();
    if (t < 128) {
        float inv_norm = 1.0f / sqrtf(wsum[0] + wsum[1]);
        v_out[(size_t)blk * FEAT + t] = pre[t] * inv_norm;
    }
}

// ---------------------------------------------------------------------------
// Kernel 2: dense skinny GEMM + exp. E[sb][n] = exp(dot(bank[n], v[sb])/T).
// R6 = R4 layout + R5 occupancy/prefetch:
//  - Thread tile: 8 CONSECUTIVE rows (rg=t>>3) x 8 anchors (ag=t&7).
//    * A-read:  8 distinct rg-broadcast b128, bank-quads (c^rg)&7 distinct
//               -> bank-balanced, conflict-free (R4 measured 0).
//    * B-read:  2-way aliased (free).
//    * Epilogue: per anchor, 8 same-ag lanes cover 64 consecutive n
//               = 256 B dense segments -> no partial-line RMW (R4: 50 MB).
//  - K in 4 passes of 32: sA 32 KB (xor-swizzled) + sB 8 KB = 40 KB LDS
//    -> 3 blocks/CU (R4's 80 KB gave only 2).
//  - Next pass's A/B prefetched into VGPRs before compute: ~900-cycle
//    global latency hides under 2048 FMAs; barrier only gates ds_write.
// ---------------------------------------------------------------------------
__global__ void __launch_bounds__(256, 3) gemm_exp_kernel(
    const float* __restrict__ mem_v1, const float* __restrict__ mem_v2,
    const float* __restrict__ v_in, float* __restrict__ E)
{
    __shared__ __align__(16) float sA[RT * KW];   // swizzled [row][f ^ ((row>>3)&7)]
    __shared__ __align__(16) float sB[KW * 64];   // [k][b]

    const int bx   = blockIdx.x;
    const int side = bx & 1;
    const int tile = bx >> 1;
    const int n0   = tile * RT;
    const float* bank = (side == 0 ? mem_v2 : mem_v1);
    const float* vb   = v_in + (size_t)side * 64 * FEAT;
    const int t  = threadIdx.x;
    const int ag = t & 7;             // anchors ag*8..+7
    const int rg = t >> 3;            // rows n0+rg*8..+7 (consecutive!)
    const int r0 = n0 + rg * 8;

    float4 pfA[8], pfB[2];

    auto loadAB = [&](int k0) {
#pragma unroll
        for (int it = 0; it < 8; ++it) {
            const int i = t + it * 256;        // 0..2047
            const int r = i >> 3, f = i & 7;   // row 0..255, float4 0..7
            int row = n0 + r; if (row > NDATA - 1) row = NDATA - 1;
            pfA[it] = *(const float4*)(bank + (size_t)row * FEAT + k0 + f * 4);
        }
#pragma unroll
        for (int it = 0; it < 2; ++it) {
            const int i = t + it * 256;        // 0..511
            const int b2 = i & 63, f = i >> 6; // anchor, float4 0..7
            pfB[it] = *(const float4*)(vb + (size_t)b2 * FEAT + k0 + f * 4);
        }
    };
    auto writeAB = [&]() {
#pragma unroll
        for (int it = 0; it < 8; ++it) {
            const int i = t + it * 256;
            const int r = i >> 3, f = i & 7;
            const int fs = f ^ ((r >> 3) & 7);           // xor swizzle
            *(float4*)&sA[r * KW + fs * 4] = pfA[it];
        }
#pragma unroll
        for (int it = 0; it < 2; ++it) {
            const int i = t + it * 256;
            const int b2 = i & 63, f = i >> 6;
            sB[(f * 4 + 0) * 64 + b2] = pfB[it].x;       // bank = b2&31: balanced
            sB[(f * 4 + 1) * 64 + b2] = pfB[it].y;
            sB[(f * 4 + 2) * 64 + b2] = pfB[it].z;
            sB[(f * 4 + 3) * 64 + b2] = pfB[it].w;
        }
    };

    float acc[8][8];
#pragma unroll
    for (int i = 0; i < 8; ++i)
#pragma unroll
        for (int j = 0; j < 8; ++j) acc[i][j] = 0.f;

    // stage pass 0
    loadAB(0);
    writeAB();
    __syncthreads();

#pragma unroll 1
    for (int p = 0; p < 4; ++p) {
        if (p < 3) loadAB((p + 1) * KW);   // prefetch next pass into VGPRs

#pragma unroll 1
        for (int c = 0; c < 8; ++c) {      // 8 chunks of 4 k
            float4 af[8], bf[8];
            const int ca = ((c ^ (rg & 7)) & 7) * 4;     // un-swizzle
#pragma unroll
            for (int i = 0; i < 8; ++i)
                af[i] = *(const float4*)&sA[(rg * 8 + i) * KW + ca];
#pragma unroll
            for (int kk = 0; kk < 4; ++kk) {
                bf[kk * 2 + 0] = *(const float4*)&sB[(c * 4 + kk) * 64 + ag * 8];
                bf[kk * 2 + 1] = *(const float4*)&sB[(c * 4 + kk) * 64 + ag * 8 + 4];
            }
#pragma unroll
            for (int kk = 0; kk < 4; ++kk)
#pragma unroll
                for (int i = 0; i < 8; ++i) {
                    const float a = (kk == 0) ? af[i].x : (kk == 1) ? af[i].y
                                  : (kk == 2) ? af[i].z : af[i].w;
                    acc[i][0] += a * bf[kk * 2].x;  acc[i][1] += a * bf[kk * 2].y;
                    acc[i][2] += a * bf[kk * 2].z;  acc[i][3] += a * bf[kk * 2].w;
                    acc[i][4] += a * bf[kk * 2 + 1].x;  acc[i][5] += a * bf[kk * 2 + 1].y;
                    acc[i][6] += a * bf[kk * 2 + 1].z;  acc[i][7] += a * bf[kk * 2 + 1].w;
                }
        }

        if (p < 3) {
            __syncthreads();     // all reads of pass p done
            writeAB();           // data already in VGPRs
            __syncthreads();
        }
    }

    // epilogue: exp + store E[sb][n]; per anchor, same-ag lanes of a wave
    // cover 64 consecutive n -> dense 256 B segments, no partial lines.
    if (r0 + 8 <= NDATA) {
#pragma unroll
        for (int j = 0; j < 8; ++j) {
            float4 o0, o1;
            o0.x = __expf(acc[0][j] * NCE_T_INV);
            o0.y = __expf(acc[1][j] * NCE_T_INV);
            o0.z = __expf(acc[2][j] * NCE_T_INV);
            o0.w = __expf(acc[3][j] * NCE_T_INV);
            o1.x = __expf(acc[4][j] * NCE_T_INV);
            o1.y = __expf(acc[5][j] * NCE_T_INV);
            o1.z = __expf(acc[6][j] * NCE_T_INV);
            o1.w = __expf(acc[7][j] * NCE_T_INV);
            float* dst = E + (size_t)(side * 64 + ag * 8 + j) * NDATA + r0;
            *(float4*)dst = o0;
            *(float4*)(dst + 4) = o1;
        }
    }
}

// ---------------------------------------------------------------------------
// Kernel 3: gather ex = E[sb][idx[b,k]], store compact, accumulate Z[sb].
// ---------------------------------------------------------------------------
__global__ void __launch_bounds__(256) gather_z_kernel(
    const int* __restrict__ sample_idx, const float* __restrict__ E,
    float* __restrict__ ex_out, float* __restrict__ z_out)
{
    const int blk   = blockIdx.x;
    const int chunk = blk >> 7;          // 0..GCH-1
    const int sb    = blk & 127;         // side*64 + b
    const int b     = sb & 63;
    const float* Eb = E + (size_t)sb * NDATA;

    float zp = 0.f;
    for (int k = chunk * 256 + threadIdx.x; k < KP1; k += GCH * 256) {
        const int idx = sample_idx[(size_t)b * KP1 + k];
        const float e = Eb[idx];
        ex_out[(size_t)sb * KP1 + k] = e;
        zp += e;
    }
#pragma unroll
    for (int o = 32; o > 0; o >>= 1) zp += __shfl_xor(zp, o, 64);
    __shared__ float zw[4];
    if ((threadIdx.x & 63) == 0) zw[threadIdx.x >> 6] = zp;
    __syncthreads();
    if (threadIdx.x == 0) atomicAdd(&z_out[sb], zw[0] + zw[1] + zw[2] + zw[3]);
}

// ---------------------------------------------------------------------------
// Kernel 4: loss. 256 blocks (2 chunks x 128 sb); Z summed in-kernel.
// ---------------------------------------------------------------------------
__global__ void __launch_bounds__(256) loss_kernel(
    const float* __restrict__ ex_in, const float* __restrict__ z_in,
    float* __restrict__ out)
{
    const int blk   = blockIdx.x;
    const int chunk = blk >> 7;          // 0..1
    const int sb    = blk & 127;
    const int side  = sb >> 6;

    __shared__ float zsh;
    if (threadIdx.x < 64) {
        float zv = z_in[side * 64 + threadIdx.x];
#pragma unroll
        for (int o = 32; o > 0; o >>= 1) zv += __shfl_xor(zv, o, 64);
        if (threadIdx.x == 0) zsh = zv;
    }
    __syncthreads();

    const float z  = zsh * ((float)NDATA / (64.0f * (float)KP1));
    const float rz = 1.0f / z;
    const float* ex = ex_in + (size_t)sb * KP1;

    float part = 0.f;
    for (int k = chunk * 256 + threadIdx.x; k < KP1; k += 512) {
        const float x = ex[k] * rz;
        if (k == 0) part += __logf(x / (x + M_CONST + EPS_C));
        else        part += __logf(M_CONST / (x + M_CONST + EPS_C));
    }
#pragma unroll
    for (int o = 32; o > 0; o >>= 1) part += __shfl_xor(part, o, 64);
    __shared__ float pw[4];
    if ((threadIdx.x & 63) == 0) pw[threadIdx.x >> 6] = part;
    __syncthreads();
    if (threadIdx.x == 0)
        atomicAdd(out, -(pw[0] + pw[1] + pw[2] + pw[3]) * (1.0f / 64.0f));
}

// ---------------------------------------------------------------------------
extern "C" void kernel_launch(void* const* d_in, const int* in_sizes, int n_in,
                              void* d_out, int out_size, void* d_ws, size_t ws_size,
                              hipStream_t stream)
{
    const float* feat_s     = (const float*)d_in[0];
    const float* feat_t     = (const float*)d_in[1];
    /* d_in[2] = idx, unused: sample_idx[:,0] already holds it */
    const int*   sample_idx = (const int*)  d_in[3];
    const float* w_s        = (const float*)d_in[4];
    const float* b_s        = (const float*)d_in[5];
    const float* w_t        = (const float*)d_in[6];
    const float* b_t        = (const float*)d_in[7];
    const float* mem_v1     = (const float*)d_in[8];
    const float* mem_v2     = (const float*)d_in[9];
    float* out = (float*)d_out;

    // Workspace layout:
    //   [z: 128 f32 = 512 B]
    //   [v: 2*64*128 f32 = 64 KB]
    //   [ex: 2*64*16385 f32 = 8.39 MB]
    //   [E: 128*100000 f32 = 51.2 MB]  (transposed: E[sb][n])
    char*  ws    = (char*)d_ws;
    float* ws_z  = (float*)ws;
    float* ws_v  = (float*)(ws + 512);
    float* ws_ex = (float*)(ws + 512 + 2 * BATCH * FEAT * sizeof(float));
    float* ws_E  = (float*)(ws + 512 + 2 * BATCH * FEAT * sizeof(float)
                               + (size_t)2 * BATCH * KP1 * sizeof(float));

    hipMemsetAsync(ws_z, 0, 128 * sizeof(float), stream);
    hipMemsetAsync(out, 0, sizeof(float), stream);

    embed_kernel<<<2 * BATCH, 256, 0, stream>>>(feat_s, feat_t, w_s, b_s, w_t, b_t, ws_v);
    gemm_exp_kernel<<<2 * NTILES, 256, 0, stream>>>(mem_v1, mem_v2, ws_v, ws_E);
    gather_z_kernel<<<2 * BATCH * GCH, 256, 0, stream>>>(sample_idx, ws_E, ws_ex, ws_z);
    loss_kernel<<<2 * BATCH * 2, 256, 0, stream>>>(ws_ex, ws_z, out);
}

// Round 7
// 312.150 us; speedup vs baseline: 1.0444x; 1.0444x over previous
//
#include <hip/hip_runtime.h>

// Problem constants (from reference)
#define DIM_IN   2048
#define FEAT     128
#define KP1      16385      // NCE_N + 1
#define NDATA    100000
#define BATCH    64
#define RT       256        // rows per gemm tile
#define KW       32         // K-pass width (4 passes of 32)
#define NTILES   ((NDATA + RT - 1) / RT)   // 391
#define GCH      8          // k-chunks per (side,b) in gather kernel

constexpr float NCE_T_INV = 1.0f / 0.07f;
constexpr float M_CONST   = 16384.0f / 100000.0f;   // NCE_N / N_DATA
constexpr float EPS_C     = 1e-7f;

// ---------------------------------------------------------------------------
// Kernel 1: h = l2norm(feat @ w.T + b). Per-wave coalesced row dots.
// ---------------------------------------------------------------------------
__global__ void __launch_bounds__(256) embed_kernel(
    const float* __restrict__ feat_s, const float* __restrict__ feat_t,
    const float* __restrict__ w_s, const float* __restrict__ b_s,
    const float* __restrict__ w_t, const float* __restrict__ b_t,
    float* __restrict__ v_out)
{
    const int blk  = blockIdx.x;      // side*64 + b
    const int side = blk >> 6;
    const int b    = blk & 63;
    const float* feat = (side == 0 ? feat_s : feat_t) + (size_t)b * DIM_IN;
    const float* w    = (side == 0 ? w_s : w_t);
    const float* bias = (side == 0 ? b_s : b_t);

    __shared__ float sfeat[DIM_IN];
    __shared__ float pre[FEAT];
    __shared__ float wsum[2];

    const int t = threadIdx.x;
    {   // coalesced float4 stage of the feat row (8 KB)
        const float4* f4 = (const float4*)feat;
        float4* s4 = (float4*)sfeat;
        for (int j = t; j < DIM_IN / 4; j += 256) s4[j] = f4[j];
    }
    __syncthreads();

    const int wv = t >> 6, ln = t & 63;
    const float4* w4  = (const float4*)w;
    const float4* sf4 = (const float4*)sfeat;
    for (int d = wv; d < FEAT; d += 4) {
        float s = 0.f;
#pragma unroll
        for (int seg = 0; seg < 8; ++seg) {      // 512 float4 per row / 64 lanes
            float4 a = w4[d * (DIM_IN / 4) + seg * 64 + ln];
            float4 f = sf4[seg * 64 + ln];
            s += a.x * f.x + a.y * f.y + a.z * f.z + a.w * f.w;
        }
#pragma unroll
        for (int o = 32; o > 0; o >>= 1) s += __shfl_xor(s, o, 64);
        if (ln == 0) pre[d] = s;
    }
    __syncthreads();

    if (t < 128) {
        float p = pre[t] + bias[t];
        pre[t] = p;
        float sq = p * p;
#pragma unroll
        for (int o = 32; o > 0; o >>= 1) sq += __shfl_xor(sq, o, 64);
        if ((t & 63) == 0) wsum[t >> 6] = sq;
    }
    __syncthreads();
    if (t < 128) {
        float inv_norm = 1.0f / sqrtf(wsum[0] + wsum[1]);
        v_out[(size_t)blk * FEAT + t] = pre[t] * inv_norm;
    }
}

// ---------------------------------------------------------------------------
// Kernel 2: dense skinny GEMM + exp. E[sb][n] = exp(dot(bank[n], v[sb])/T).
// R7 = R4's register-clean structure (VGPR 112, zero spill, zero conflicts,
// WRITE=50MB) with two deltas:
//  - KW=32 (4 passes): LDS 40 KB -> 4 blocks/CU (4 x 40 = 160 KB exactly).
//    Latency hiding via TLP (4 resident blocks in staggered phases), NOT
//    via VGPR-held prefetch (R5/R6 lesson: held arrays + high-occ register
//    allocator target => scratch spills => +180 MB HBM traffic).
//  - amdgpu_waves_per_eu(4,4) pins the allocator at 128 VGPRs so it cannot
//    voluntarily chase 6-8 waves/EU and spill (R6: VGPR=84 w/ 150 live).
// Thread tile: 8 consecutive rows (rg) x 8 anchors (ag); sA xor-swizzled
// (measured 0 conflicts in R4); epilogue = dense 256B segments per anchor.
// ---------------------------------------------------------------------------
__global__ void __attribute__((amdgpu_waves_per_eu(4, 4)))
__launch_bounds__(256) gemm_exp_kernel(
    const float* __restrict__ mem_v1, const float* __restrict__ mem_v2,
    const float* __restrict__ v_in, float* __restrict__ E)
{
    __shared__ __align__(16) float sA[RT * KW];   // swizzled [row][f ^ ((row>>3)&7)]
    __shared__ __align__(16) float sB[KW * 64];   // [k][b]

    const int bx   = blockIdx.x;
    const int side = bx & 1;
    const int tile = bx >> 1;
    const int n0   = tile * RT;
    const float* bank = (side == 0 ? mem_v2 : mem_v1);
    const float* vb   = v_in + (size_t)side * 64 * FEAT;
    const int t  = threadIdx.x;
    const int ag = t & 7;             // anchors ag*8..+7
    const int rg = t >> 3;            // rows n0+rg*8..+7 (consecutive)
    const int r0 = n0 + rg * 8;

    float acc[8][8];
#pragma unroll
    for (int i = 0; i < 8; ++i)
#pragma unroll
        for (int j = 0; j < 8; ++j) acc[i][j] = 0.f;

#pragma unroll 1
    for (int p = 0; p < 4; ++p) {
        if (p > 0) __syncthreads();   // previous pass's LDS reads complete

        // ---- stage pass p: transient regs only (no cross-pass holding) ----
        {
            float4 sa[8];
#pragma unroll
            for (int it = 0; it < 8; ++it) {
                const int i = t + it * 256;        // 0..2047
                const int r = i >> 3, f = i & 7;   // row 0..255, float4 0..7
                int row = n0 + r; if (row > NDATA - 1) row = NDATA - 1;
                sa[it] = *(const float4*)(bank + (size_t)row * FEAT + p * KW + f * 4);
            }
            float4 sbv[2];
#pragma unroll
            for (int it = 0; it < 2; ++it) {
                const int i = t + it * 256;        // 0..511
                const int b2 = i & 63, f = i >> 6;
                sbv[it] = *(const float4*)(vb + (size_t)b2 * FEAT + p * KW + f * 4);
            }
#pragma unroll
            for (int it = 0; it < 8; ++it) {
                const int i = t + it * 256;
                const int r = i >> 3, f = i & 7;
                const int fs = f ^ ((r >> 3) & 7);           // xor swizzle
                *(float4*)&sA[r * KW + fs * 4] = sa[it];
            }
#pragma unroll
            for (int it = 0; it < 2; ++it) {
                const int i = t + it * 256;
                const int b2 = i & 63, f = i >> 6;
                sB[(f * 4 + 0) * 64 + b2] = sbv[it].x;       // bank=b2&31: balanced
                sB[(f * 4 + 1) * 64 + b2] = sbv[it].y;
                sB[(f * 4 + 2) * 64 + b2] = sbv[it].z;
                sB[(f * 4 + 3) * 64 + b2] = sbv[it].w;
            }
        }
        __syncthreads();

        // ---- compute pass p: 8 chunks of 4 k ----
#pragma unroll 1
        for (int c = 0; c < 8; ++c) {
            float4 af[8], bf[8];
            const int ca = ((c ^ (rg & 7)) & 7) * 4;         // un-swizzle
#pragma unroll
            for (int i = 0; i < 8; ++i)
                af[i] = *(const float4*)&sA[(rg * 8 + i) * KW + ca];
#pragma unroll
            for (int kk = 0; kk < 4; ++kk) {
                bf[kk * 2 + 0] = *(const float4*)&sB[(c * 4 + kk) * 64 + ag * 8];
                bf[kk * 2 + 1] = *(const float4*)&sB[(c * 4 + kk) * 64 + ag * 8 + 4];
            }
#pragma unroll
            for (int kk = 0; kk < 4; ++kk)
#pragma unroll
                for (int i = 0; i < 8; ++i) {
                    const float a = (kk == 0) ? af[i].x : (kk == 1) ? af[i].y
                                  : (kk == 2) ? af[i].z : af[i].w;
                    acc[i][0] += a * bf[kk * 2].x;  acc[i][1] += a * bf[kk * 2].y;
                    acc[i][2] += a * bf[kk * 2].z;  acc[i][3] += a * bf[kk * 2].w;
                    acc[i][4] += a * bf[kk * 2 + 1].x;  acc[i][5] += a * bf[kk * 2 + 1].y;
                    acc[i][6] += a * bf[kk * 2 + 1].z;  acc[i][7] += a * bf[kk * 2 + 1].w;
                }
        }
    }

    // epilogue: exp + store E[sb][n]; per anchor, same-ag lanes of a wave
    // cover 64 consecutive n -> dense 256 B segments (R4 measured 50 MB).
    if (r0 + 8 <= NDATA) {
#pragma unroll
        for (int j = 0; j < 8; ++j) {
            float4 o0, o1;
            o0.x = __expf(acc[0][j] * NCE_T_INV);
            o0.y = __expf(acc[1][j] * NCE_T_INV);
            o0.z = __expf(acc[2][j] * NCE_T_INV);
            o0.w = __expf(acc[3][j] * NCE_T_INV);
            o1.x = __expf(acc[4][j] * NCE_T_INV);
            o1.y = __expf(acc[5][j] * NCE_T_INV);
            o1.z = __expf(acc[6][j] * NCE_T_INV);
            o1.w = __expf(acc[7][j] * NCE_T_INV);
            float* dst = E + (size_t)(side * 64 + ag * 8 + j) * NDATA + r0;
            *(float4*)dst = o0;
            *(float4*)(dst + 4) = o1;
        }
    }
}

// ---------------------------------------------------------------------------
// Kernel 3: gather ex = E[sb][idx[b,k]], store compact, accumulate Z[sb].
// ---------------------------------------------------------------------------
__global__ void __launch_bounds__(256) gather_z_kernel(
    const int* __restrict__ sample_idx, const float* __restrict__ E,
    float* __restrict__ ex_out, float* __restrict__ z_out)
{
    const int blk   = blockIdx.x;
    const int chunk = blk >> 7;          // 0..GCH-1
    const int sb    = blk & 127;         // side*64 + b
    const int b     = sb & 63;
    const float* Eb = E + (size_t)sb * NDATA;

    float zp = 0.f;
    for (int k = chunk * 256 + threadIdx.x; k < KP1; k += GCH * 256) {
        const int idx = sample_idx[(size_t)b * KP1 + k];
        const float e = Eb[idx];
        ex_out[(size_t)sb * KP1 + k] = e;
        zp += e;
    }
#pragma unroll
    for (int o = 32; o > 0; o >>= 1) zp += __shfl_xor(zp, o, 64);
    __shared__ float zw[4];
    if ((threadIdx.x & 63) == 0) zw[threadIdx.x >> 6] = zp;
    __syncthreads();
    if (threadIdx.x == 0) atomicAdd(&z_out[sb], zw[0] + zw[1] + zw[2] + zw[3]);
}

// ---------------------------------------------------------------------------
// Kernel 4: loss. 256 blocks (2 chunks x 128 sb); Z summed in-kernel.
// ---------------------------------------------------------------------------
__global__ void __launch_bounds__(256) loss_kernel(
    const float* __restrict__ ex_in, const float* __restrict__ z_in,
    float* __restrict__ out)
{
    const int blk   = blockIdx.x;
    const int chunk = blk >> 7;          // 0..1
    const int sb    = blk & 127;
    const int side  = sb >> 6;

    __shared__ float zsh;
    if (threadIdx.x < 64) {
        float zv = z_in[side * 64 + threadIdx.x];
#pragma unroll
        for (int o = 32; o > 0; o >>= 1) zv += __shfl_xor(zv, o, 64);
        if (threadIdx.x == 0) zsh = zv;
    }
    __syncthreads();

    const float z  = zsh * ((float)NDATA / (64.0f * (float)KP1));
    const float rz = 1.0f / z;
    const float* ex = ex_in + (size_t)sb * KP1;

    float part = 0.f;
    for (int k = chunk * 256 + threadIdx.x; k < KP1; k += 512) {
        const float x = ex[k] * rz;
        if (k == 0) part += __logf(x / (x + M_CONST + EPS_C));
        else        part += __logf(M_CONST / (x + M_CONST + EPS_C));
    }
#pragma unroll
    for (int o = 32; o > 0; o >>= 1) part += __shfl_xor(part, o, 64);
    __shared__ float pw[4];
    if ((threadIdx.x & 63) == 0) pw[threadIdx.x >> 6] = part;
    __syncthreads();
    if (threadIdx.x == 0)
        atomicAdd(out, -(pw[0] + pw[1] + pw[2] + pw[3]) * (1.0f / 64.0f));
}

// ---------------------------------------------------------------------------
extern "C" void kernel_launch(void* const* d_in, const int* in_sizes, int n_in,
                              void* d_out, int out_size, void* d_ws, size_t ws_size,
                              hipStream_t stream)
{
    const float* feat_s     = (const float*)d_in[0];
    const float* feat_t     = (const float*)d_in[1];
    /* d_in[2] = idx, unused: sample_idx[:,0] already holds it */
    const int*   sample_idx = (const int*)  d_in[3];
    const float* w_s        = (const float*)d_in[4];
    const float* b_s        = (const float*)d_in[5];
    const float* w_t        = (const float*)d_in[6];
    const float* b_t        = (const float*)d_in[7];
    const float* mem_v1     = (const float*)d_in[8];
    const float* mem_v2     = (const float*)d_in[9];
    float* out = (float*)d_out;

    // Workspace layout:
    //   [z: 128 f32 = 512 B]
    //   [v: 2*64*128 f32 = 64 KB]
    //   [ex: 2*64*16385 f32 = 8.39 MB]
    //   [E: 128*100000 f32 = 51.2 MB]  (transposed: E[sb][n])
    char*  ws    = (char*)d_ws;
    float* ws_z  = (float*)ws;
    float* ws_v  = (float*)(ws + 512);
    float* ws_ex = (float*)(ws + 512 + 2 * BATCH * FEAT * sizeof(float));
    float* ws_E  = (float*)(ws + 512 + 2 * BATCH * FEAT * sizeof(float)
                               + (size_t)2 * BATCH * KP1 * sizeof(float));

    hipMemsetAsync(ws_z, 0, 128 * sizeof(float), stream);
    hipMemsetAsync(out, 0, sizeof(float), stream);

    embed_kernel<<<2 * BATCH, 256, 0, stream>>>(feat_s, feat_t, w_s, b_s, w_t, b_t, ws_v);
    gemm_exp_kernel<<<2 * NTILES, 256, 0, stream>>>(mem_v1, mem_v2, ws_v, ws_E);
    gather_z_kernel<<<2 * BATCH * GCH, 256, 0, stream>>>(sample_idx, ws_E, ws_ex, ws_z);
    loss_kernel<<<2 * BATCH * 2, 256, 0, stream>>>(ws_ex, ws_z, out);
}

// Round 8
// 262.490 us; speedup vs baseline: 1.2420x; 1.1892x over previous
//
#include <hip/hip_runtime.h>

// Problem constants (from reference)
#define DIM_IN   2048
#define FEAT     128
#define KP1      16385      // NCE_N + 1
#define NDATA    100000
#define BATCH    64
#define RT       256        // rows per gemm tile
#define KW       32         // K-pass width (4 passes of 32)
#define NTILES   ((NDATA + RT - 1) / RT)   // 391
#define GCH      8          // k-chunks per (side,b) in gather kernel

constexpr float NCE_T_INV = 1.0f / 0.07f;
constexpr float M_CONST   = 16384.0f / 100000.0f;   // NCE_N / N_DATA
constexpr float EPS_C     = 1e-7f;

// ---------------------------------------------------------------------------
// Kernel 1: h = l2norm(feat @ w.T + b). Per-wave coalesced row dots.
// ---------------------------------------------------------------------------
__global__ void __launch_bounds__(256) embed_kernel(
    const float* __restrict__ feat_s, const float* __restrict__ feat_t,
    const float* __restrict__ w_s, const float* __restrict__ b_s,
    const float* __restrict__ w_t, const float* __restrict__ b_t,
    float* __restrict__ v_out)
{
    const int blk  = blockIdx.x;      // side*64 + b
    const int side = blk >> 6;
    const int b    = blk & 63;
    const float* feat = (side == 0 ? feat_s : feat_t) + (size_t)b * DIM_IN;
    const float* w    = (side == 0 ? w_s : w_t);
    const float* bias = (side == 0 ? b_s : b_t);

    __shared__ float sfeat[DIM_IN];
    __shared__ float pre[FEAT];
    __shared__ float wsum[2];

    const int t = threadIdx.x;
    {   // coalesced float4 stage of the feat row (8 KB)
        const float4* f4 = (const float4*)feat;
        float4* s4 = (float4*)sfeat;
        for (int j = t; j < DIM_IN / 4; j += 256) s4[j] = f4[j];
    }
    __syncthreads();

    const int wv = t >> 6, ln = t & 63;
    const float4* w4  = (const float4*)w;
    const float4* sf4 = (const float4*)sfeat;
    for (int d = wv; d < FEAT; d += 4) {
        float s = 0.f;
#pragma unroll
        for (int seg = 0; seg < 8; ++seg) {      // 512 float4 per row / 64 lanes
            float4 a = w4[d * (DIM_IN / 4) + seg * 64 + ln];
            float4 f = sf4[seg * 64 + ln];
            s += a.x * f.x + a.y * f.y + a.z * f.z + a.w * f.w;
        }
#pragma unroll
        for (int o = 32; o > 0; o >>= 1) s += __shfl_xor(s, o, 64);
        if (ln == 0) pre[d] = s;
    }
    __syncthreads();

    if (t < 128) {
        float p = pre[t] + bias[t];
        pre[t] = p;
        float sq = p * p;
#pragma unroll
        for (int o = 32; o > 0; o >>= 1) sq += __shfl_xor(sq, o, 64);
        if ((t & 63) == 0) wsum[t >> 6] = sq;
    }
    __syncthreads();
    if (t < 128) {
        float inv_norm = 1.0f / sqrtf(wsum[0] + wsum[1]);
        v_out[(size_t)blk * FEAT + t] = pre[t] * inv_norm;
    }
}

// ---------------------------------------------------------------------------
// Kernel 2: dense skinny GEMM + exp. E[sb][n] = exp(dot(bank[n], v[sb])/T).
// R8 = R7 body with the declaration reverted to __launch_bounds__(256, 2).
// Allocator law from 7 rounds of evidence (VGPR_Count -> spill traffic):
//   (256,2) -> 112, ZERO spill (R4: WRITE exactly 50 MB)   <- the only clean one
//   (256,3) -> 68-84, spills held arrays (R5/R6: +100-180 MB HBM)
//   waves_per_eu(4,4) -> 64, spills acc (R7: +90 MB)
// At VGPR=112: floor(512/112) = 4 waves/SIMD = 4 blocks/CU, matching the
// LDS limit (4 x 40 KB = 160 KB). Cross-block TLP (4 staggered blocks)
// hides stage/compute barriers -- no VGPR-held prefetch needed.
// Thread tile: 8 consecutive rows (rg) x 8 anchors (ag); sA xor-swizzled
// (measured 0 conflicts since R4); epilogue = dense 256 B segments/anchor.
// ---------------------------------------------------------------------------
__global__ void __launch_bounds__(256, 2) gemm_exp_kernel(
    const float* __restrict__ mem_v1, const float* __restrict__ mem_v2,
    const float* __restrict__ v_in, float* __restrict__ E)
{
    __shared__ __align__(16) float sA[RT * KW];   // swizzled [row][f ^ ((row>>3)&7)]
    __shared__ __align__(16) float sB[KW * 64];   // [k][b]

    const int bx   = blockIdx.x;
    const int side = bx & 1;
    const int tile = bx >> 1;
    const int n0   = tile * RT;
    const float* bank = (side == 0 ? mem_v2 : mem_v1);
    const float* vb   = v_in + (size_t)side * 64 * FEAT;
    const int t  = threadIdx.x;
    const int ag = t & 7;             // anchors ag*8..+7
    const int rg = t >> 3;            // rows n0+rg*8..+7 (consecutive)
    const int r0 = n0 + rg * 8;

    float acc[8][8];
#pragma unroll
    for (int i = 0; i < 8; ++i)
#pragma unroll
        for (int j = 0; j < 8; ++j) acc[i][j] = 0.f;

#pragma unroll 1
    for (int p = 0; p < 4; ++p) {
        if (p > 0) __syncthreads();   // previous pass's LDS reads complete

        // ---- stage pass p: transient regs only (no cross-pass holding) ----
        {
            float4 sa[8];
#pragma unroll
            for (int it = 0; it < 8; ++it) {
                const int i = t + it * 256;        // 0..2047
                const int r = i >> 3, f = i & 7;   // row 0..255, float4 0..7
                int row = n0 + r; if (row > NDATA - 1) row = NDATA - 1;
                sa[it] = *(const float4*)(bank + (size_t)row * FEAT + p * KW + f * 4);
            }
            float4 sbv[2];
#pragma unroll
            for (int it = 0; it < 2; ++it) {
                const int i = t + it * 256;        // 0..511
                const int b2 = i & 63, f = i >> 6;
                sbv[it] = *(const float4*)(vb + (size_t)b2 * FEAT + p * KW + f * 4);
            }
#pragma unroll
            for (int it = 0; it < 8; ++it) {
                const int i = t + it * 256;
                const int r = i >> 3, f = i & 7;
                const int fs = f ^ ((r >> 3) & 7);           // xor swizzle
                *(float4*)&sA[r * KW + fs * 4] = sa[it];
            }
#pragma unroll
            for (int it = 0; it < 2; ++it) {
                const int i = t + it * 256;
                const int b2 = i & 63, f = i >> 6;
                sB[(f * 4 + 0) * 64 + b2] = sbv[it].x;       // bank=b2&31: balanced
                sB[(f * 4 + 1) * 64 + b2] = sbv[it].y;
                sB[(f * 4 + 2) * 64 + b2] = sbv[it].z;
                sB[(f * 4 + 3) * 64 + b2] = sbv[it].w;
            }
        }
        __syncthreads();

        // ---- compute pass p: 8 chunks of 4 k ----
#pragma unroll 1
        for (int c = 0; c < 8; ++c) {
            float4 af[8], bf[8];
            const int ca = ((c ^ (rg & 7)) & 7) * 4;         // un-swizzle
#pragma unroll
            for (int i = 0; i < 8; ++i)
                af[i] = *(const float4*)&sA[(rg * 8 + i) * KW + ca];
#pragma unroll
            for (int kk = 0; kk < 4; ++kk) {
                bf[kk * 2 + 0] = *(const float4*)&sB[(c * 4 + kk) * 64 + ag * 8];
                bf[kk * 2 + 1] = *(const float4*)&sB[(c * 4 + kk) * 64 + ag * 8 + 4];
            }
#pragma unroll
            for (int kk = 0; kk < 4; ++kk)
#pragma unroll
                for (int i = 0; i < 8; ++i) {
                    const float a = (kk == 0) ? af[i].x : (kk == 1) ? af[i].y
                                  : (kk == 2) ? af[i].z : af[i].w;
                    acc[i][0] += a * bf[kk * 2].x;  acc[i][1] += a * bf[kk * 2].y;
                    acc[i][2] += a * bf[kk * 2].z;  acc[i][3] += a * bf[kk * 2].w;
                    acc[i][4] += a * bf[kk * 2 + 1].x;  acc[i][5] += a * bf[kk * 2 + 1].y;
                    acc[i][6] += a * bf[kk * 2 + 1].z;  acc[i][7] += a * bf[kk * 2 + 1].w;
                }
        }
    }

    // epilogue: exp + store E[sb][n]; per anchor, same-ag lanes of a wave
    // cover 64 consecutive n -> dense 256 B segments (R4 measured 50 MB).
    if (r0 + 8 <= NDATA) {
#pragma unroll
        for (int j = 0; j < 8; ++j) {
            float4 o0, o1;
            o0.x = __expf(acc[0][j] * NCE_T_INV);
            o0.y = __expf(acc[1][j] * NCE_T_INV);
            o0.z = __expf(acc[2][j] * NCE_T_INV);
            o0.w = __expf(acc[3][j] * NCE_T_INV);
            o1.x = __expf(acc[4][j] * NCE_T_INV);
            o1.y = __expf(acc[5][j] * NCE_T_INV);
            o1.z = __expf(acc[6][j] * NCE_T_INV);
            o1.w = __expf(acc[7][j] * NCE_T_INV);
            float* dst = E + (size_t)(side * 64 + ag * 8 + j) * NDATA + r0;
            *(float4*)dst = o0;
            *(float4*)(dst + 4) = o1;
        }
    }
}

// ---------------------------------------------------------------------------
// Kernel 3: gather ex = E[sb][idx[b,k]], store compact, accumulate Z[sb].
// ---------------------------------------------------------------------------
__global__ void __launch_bounds__(256) gather_z_kernel(
    const int* __restrict__ sample_idx, const float* __restrict__ E,
    float* __restrict__ ex_out, float* __restrict__ z_out)
{
    const int blk   = blockIdx.x;
    const int chunk = blk >> 7;          // 0..GCH-1
    const int sb    = blk & 127;         // side*64 + b
    const int b     = sb & 63;
    const float* Eb = E + (size_t)sb * NDATA;

    float zp = 0.f;
    for (int k = chunk * 256 + threadIdx.x; k < KP1; k += GCH * 256) {
        const int idx = sample_idx[(size_t)b * KP1 + k];
        const float e = Eb[idx];
        ex_out[(size_t)sb * KP1 + k] = e;
        zp += e;
    }
#pragma unroll
    for (int o = 32; o > 0; o >>= 1) zp += __shfl_xor(zp, o, 64);
    __shared__ float zw[4];
    if ((threadIdx.x & 63) == 0) zw[threadIdx.x >> 6] = zp;
    __syncthreads();
    if (threadIdx.x == 0) atomicAdd(&z_out[sb], zw[0] + zw[1] + zw[2] + zw[3]);
}

// ---------------------------------------------------------------------------
// Kernel 4: loss. 256 blocks (2 chunks x 128 sb); Z summed in-kernel.
// ---------------------------------------------------------------------------
__global__ void __launch_bounds__(256) loss_kernel(
    const float* __restrict__ ex_in, const float* __restrict__ z_in,
    float* __restrict__ out)
{
    const int blk   = blockIdx.x;
    const int chunk = blk >> 7;          // 0..1
    const int sb    = blk & 127;
    const int side  = sb >> 6;

    __shared__ float zsh;
    if (threadIdx.x < 64) {
        float zv = z_in[side * 64 + threadIdx.x];
#pragma unroll
        for (int o = 32; o > 0; o >>= 1) zv += __shfl_xor(zv, o, 64);
        if (threadIdx.x == 0) zsh = zv;
    }
    __syncthreads();

    const float z  = zsh * ((float)NDATA / (64.0f * (float)KP1));
    const float rz = 1.0f / z;
    const float* ex = ex_in + (size_t)sb * KP1;

    float part = 0.f;
    for (int k = chunk * 256 + threadIdx.x; k < KP1; k += 512) {
        const float x = ex[k] * rz;
        if (k == 0) part += __logf(x / (x + M_CONST + EPS_C));
        else        part += __logf(M_CONST / (x + M_CONST + EPS_C));
    }
#pragma unroll
    for (int o = 32; o > 0; o >>= 1) part += __shfl_xor(part, o, 64);
    __shared__ float pw[4];
    if ((threadIdx.x & 63) == 0) pw[threadIdx.x >> 6] = part;
    __syncthreads();
    if (threadIdx.x == 0)
        atomicAdd(out, -(pw[0] + pw[1] + pw[2] + pw[3]) * (1.0f / 64.0f));
}

// ---------------------------------------------------------------------------
extern "C" void kernel_launch(void* const* d_in, const int* in_sizes, int n_in,
                              void* d_out, int out_size, void* d_ws, size_t ws_size,
                              hipStream_t stream)
{
    const float* feat_s     = (const float*)d_in[0];
    const float* feat_t     = (const float*)d_in[1];
    /* d_in[2] = idx, unused: sample_idx[:,0] already holds it */
    const int*   sample_idx = (const int*)  d_in[3];
    const float* w_s        = (const float*)d_in[4];
    const float* b_s        = (const float*)d_in[5];
    const float* w_t        = (const float*)d_in[6];
    const float* b_t        = (const float*)d_in[7];
    const float* mem_v1     = (const float*)d_in[8];
    const float* mem_v2     = (const float*)d_in[9];
    float* out = (float*)d_out;

    // Workspace layout:
    //   [z: 128 f32 = 512 B]
    //   [v: 2*64*128 f32 = 64 KB]
    //   [ex: 2*64*16385 f32 = 8.39 MB]
    //   [E: 128*100000 f32 = 51.2 MB]  (transposed: E[sb][n])
    char*  ws    = (char*)d_ws;
    float* ws_z  = (float*)ws;
    float* ws_v  = (float*)(ws + 512);
    float* ws_ex = (float*)(ws + 512 + 2 * BATCH * FEAT * sizeof(float));
    float* ws_E  = (float*)(ws + 512 + 2 * BATCH * FEAT * sizeof(float)
                               + (size_t)2 * BATCH * KP1 * sizeof(float));

    hipMemsetAsync(ws_z, 0, 128 * sizeof(float), stream);
    hipMemsetAsync(out, 0, sizeof(float), stream);

    embed_kernel<<<2 * BATCH, 256, 0, stream>>>(feat_s, feat_t, w_s, b_s, w_t, b_t, ws_v);
    gemm_exp_kernel<<<2 * NTILES, 256, 0, stream>>>(mem_v1, mem_v2, ws_v, ws_E);
    gather_z_kernel<<<2 * BATCH * GCH, 256, 0, stream>>>(sample_idx, ws_E, ws_ex, ws_z);
    loss_kernel<<<2 * BATCH * 2, 256, 0, stream>>>(ws_ex, ws_z, out);
}